// Round 1
// baseline (625.042 us; speedup 1.0000x reference)
//
#include <hip/hip_runtime.h>
#include <cstdint>

#define HID 1024
#define FFN 4096
#define NE 8
#define NT 4096

typedef __bf16 bf16x8 __attribute__((ext_vector_type(8)));
typedef unsigned short ushortx8 __attribute__((ext_vector_type(8)));
typedef float f32x4 __attribute__((ext_vector_type(4)));

// ---- ws layout (bytes) ----
// 0    : int   counts[8]
// 32   : int   cursor[8]
// 64   : float prob_sum[8]
// 96   : int   offsets[8]
// 256  : int   perm[NT]
// 16640: float wgt[NT]
// 33024: int   eidx[NT]
// 65536: ushort hbuf[NT*FFN]   (bf16 activations, 33.5 MB)

__device__ __forceinline__ unsigned pk_bf16(float a, float b) {
  unsigned ua = __float_as_uint(a), ub = __float_as_uint(b);
  ua = (ua + 0x7fffu + ((ua >> 16) & 1u)) >> 16;
  ub = (ub + 0x7fffu + ((ub >> 16) & 1u)) >> 16;
  return ua | (ub << 16);
}
__device__ __forceinline__ unsigned short f2bf(float a) {
  unsigned ua = __float_as_uint(a);
  return (unsigned short)((ua + 0x7fffu + ((ua >> 16) & 1u)) >> 16);
}

// ---------------- router: fp32 exact, one wave per token ----------------
__global__ __launch_bounds__(256) void router_kernel(
    const float* __restrict__ x, const float* __restrict__ rw,
    int* __restrict__ counts, float* __restrict__ prob_sum,
    int* __restrict__ eidx, float* __restrict__ wgt) {
  __shared__ float rsm[NE * HID];
  __shared__ float pshare[4][NE];
  for (int i = threadIdx.x; i < NE * HID; i += 256) rsm[i] = rw[i];
  __syncthreads();
  int wave = threadIdx.x >> 6, lane = threadIdx.x & 63;
  int t = blockIdx.x * 4 + wave;
  const float* xr = x + (size_t)t * HID;
  float acc[NE];
#pragma unroll
  for (int e = 0; e < NE; e++) acc[e] = 0.f;
#pragma unroll
  for (int j = 0; j < HID / 64; j++) {
    float xv = xr[j * 64 + lane];
#pragma unroll
    for (int e = 0; e < NE; e++) acc[e] = fmaf(xv, rsm[e * HID + j * 64 + lane], acc[e]);
  }
#pragma unroll
  for (int off = 32; off > 0; off >>= 1) {
#pragma unroll
    for (int e = 0; e < NE; e++) acc[e] += __shfl_down(acc[e], off);
  }
  if (lane == 0) {
    float mx = acc[0]; int mi = 0;
#pragma unroll
    for (int e = 1; e < NE; e++) if (acc[e] > mx) { mx = acc[e]; mi = e; }
    float pr[NE], se = 0.f;
#pragma unroll
    for (int e = 0; e < NE; e++) { pr[e] = expf(acc[e] - mx); se += pr[e]; }
    float inv = 1.f / se;
    wgt[t] = pr[mi] * inv;
    eidx[t] = mi;
    atomicAdd(&counts[mi], 1);
#pragma unroll
    for (int e = 0; e < NE; e++) pshare[wave][e] = pr[e] * inv;
  }
  __syncthreads();
  if (threadIdx.x < NE) {
    float s = pshare[0][threadIdx.x] + pshare[1][threadIdx.x] +
              pshare[2][threadIdx.x] + pshare[3][threadIdx.x];
    atomicAdd(&prob_sum[threadIdx.x], s);
  }
}

// ---------------- offsets scan + aux loss ----------------
__global__ void scan_aux_kernel(const int* __restrict__ counts,
                                const float* __restrict__ prob_sum,
                                int* __restrict__ offsets,
                                float* __restrict__ aux_out) {
  if (threadIdx.x == 0) {
    int off = 0; float s = 0.f;
    for (int e = 0; e < NE; e++) {
      offsets[e] = off;
      off += counts[e];
      s += (prob_sum[e] / (float)NT) * ((float)counts[e] / (float)NT);
    }
    *aux_out = 0.01f * (float)NE * s;
  }
}

// ---------------- group tokens by expert ----------------
__global__ void bucketize_kernel(const int* __restrict__ eidx,
                                 const int* __restrict__ offsets,
                                 int* __restrict__ cursor, int* __restrict__ perm) {
  int t = blockIdx.x * 256 + threadIdx.x;
  int e = eidx[t];
  int slot = atomicAdd(&cursor[e], 1);
  perm[offsets[e] + slot] = t;
}

// ---------------- GEMM1: H = gelu(X W1^T + b1), bf16 MFMA ----------------
// C tile 128x128, 4 waves (2x2), each wave 4x4 of 16x16x32.
__global__ __launch_bounds__(256) void gemm1_kernel(
    const float* __restrict__ x, const float* __restrict__ w1,
    const float* __restrict__ b1, const int* __restrict__ counts,
    const int* __restrict__ offsets, const int* __restrict__ perm,
    unsigned short* __restrict__ hbuf) {
  int e = blockIdx.z;
  int Nexp = counts[e];
  int m0 = blockIdx.y * 128;
  if (m0 >= Nexp) return;
  int n0 = blockIdx.x * 128;
  int obase = offsets[e];
  int gbase = obase + m0;

  __shared__ unsigned short As[128 * 40];   // padded stride 40 (80B, 16B-aligned)
  __shared__ unsigned short Bs[128 * 40];
  __shared__ int toks[128];

  int tid = threadIdx.x;
  if (tid < 128) {
    int r = m0 + tid;
    toks[tid] = perm[obase + (r < Nexp ? r : Nexp - 1)];
  }
  __syncthreads();

  int tr = tid >> 3;   // 0..31
  int tc = tid & 7;    // 0..7 -> float4 col
  const float* w1e = w1 + (size_t)e * FFN * HID;
  const float* aptr[4];
  const float* bptr[4];
#pragma unroll
  for (int i = 0; i < 4; i++) {
    aptr[i] = x + (size_t)toks[tr + 32 * i] * HID + tc * 4;
    bptr[i] = w1e + (size_t)(n0 + tr + 32 * i) * HID + tc * 4;
  }

  int lane = tid & 63, w = tid >> 6;
  int wm = w & 1, wn = w >> 1;
  int quad = lane >> 4, l15 = lane & 15;
  f32x4 acc[4][4] = {};
  const int std_idx = tr * 40 + tc * 4;

  for (int kk = 0; kk < HID / 32; kk++) {
#pragma unroll
    for (int i = 0; i < 4; i++) {
      float4 av = *(const float4*)(aptr[i] + kk * 32);
      float4 bv = *(const float4*)(bptr[i] + kk * 32);
      uint2 ap; ap.x = pk_bf16(av.x, av.y); ap.y = pk_bf16(av.z, av.w);
      uint2 bp; bp.x = pk_bf16(bv.x, bv.y); bp.y = pk_bf16(bv.z, bv.w);
      *(uint2*)&As[std_idx + i * 32 * 40] = ap;
      *(uint2*)&Bs[std_idx + i * 32 * 40] = bp;
    }
    __syncthreads();
    bf16x8 af[4], bfr[4];
#pragma unroll
    for (int mt = 0; mt < 4; mt++) {
      ushortx8 raw = *(const ushortx8*)&As[(wm * 64 + mt * 16 + l15) * 40 + quad * 8];
      af[mt] = __builtin_bit_cast(bf16x8, raw);
    }
#pragma unroll
    for (int nt = 0; nt < 4; nt++) {
      ushortx8 raw = *(const ushortx8*)&Bs[(wn * 64 + nt * 16 + l15) * 40 + quad * 8];
      bfr[nt] = __builtin_bit_cast(bf16x8, raw);
    }
#pragma unroll
    for (int mt = 0; mt < 4; mt++)
#pragma unroll
      for (int nt = 0; nt < 4; nt++)
        acc[mt][nt] = __builtin_amdgcn_mfma_f32_16x16x32_bf16(af[mt], bfr[nt], acc[mt][nt], 0, 0, 0);
    __syncthreads();
  }

  int mrem = Nexp - m0;
#pragma unroll
  for (int mt = 0; mt < 4; mt++) {
    int rbase = wm * 64 + mt * 16 + quad * 4;
#pragma unroll
    for (int nt = 0; nt < 4; nt++) {
      int col = wn * 64 + nt * 16 + l15;
      float bb = b1[e * FFN + n0 + col];
#pragma unroll
      for (int r = 0; r < 4; r++) {
        int rr = rbase + r;
        if (rr < mrem) {
          float v = acc[mt][nt][r] + bb;
          v = 0.5f * v * (1.0f + erff(v * 0.70710678118654752f));  // exact gelu
          hbuf[(size_t)(gbase + rr) * FFN + n0 + col] = f2bf(v);
        }
      }
    }
  }
}

// ---------------- GEMM2: Out = (H W2^T + b2) * gate, scatter ----------------
__global__ __launch_bounds__(256) void gemm2_kernel(
    const unsigned short* __restrict__ hbuf, const float* __restrict__ w2,
    const float* __restrict__ b2, const int* __restrict__ counts,
    const int* __restrict__ offsets, const int* __restrict__ perm,
    const float* __restrict__ wgt, float* __restrict__ out) {
  int e = blockIdx.z;
  int Nexp = counts[e];
  int m0 = blockIdx.y * 128;
  if (m0 >= Nexp) return;
  int n0 = blockIdx.x * 128;
  int obase = offsets[e];
  int gbase = obase + m0;

  __shared__ unsigned short As[128 * 40];
  __shared__ unsigned short Bs[128 * 40];
  __shared__ int toks[128];
  __shared__ float wsh[128];

  int tid = threadIdx.x;
  if (tid < 128) {
    int r = m0 + tid;
    int tk = perm[obase + (r < Nexp ? r : Nexp - 1)];
    toks[tid] = tk;
    wsh[tid] = wgt[tk];
  }
  __syncthreads();

  // A staging: bf16 rows of hbuf, 16B per thread x2 rows
  int tr2 = tid >> 2, tc2 = tid & 3;   // rows 0..63 (+64), cols of 8 bf16
  int g0 = gbase + tr2;     if (g0 > NT - 1) g0 = NT - 1;
  int g1 = gbase + tr2 + 64; if (g1 > NT - 1) g1 = NT - 1;
  const unsigned short* ap0 = hbuf + (size_t)g0 * FFN + tc2 * 8;
  const unsigned short* ap1 = hbuf + (size_t)g1 * FFN + tc2 * 8;

  // B staging: fp32 fc2_w rows, convert
  int tr = tid >> 3, tc = tid & 7;
  const float* w2e = w2 + (size_t)e * HID * FFN;
  const float* bptr[4];
#pragma unroll
  for (int i = 0; i < 4; i++)
    bptr[i] = w2e + (size_t)(n0 + tr + 32 * i) * FFN + tc * 4;

  int lane = tid & 63, w = tid >> 6;
  int wm = w & 1, wn = w >> 1;
  int quad = lane >> 4, l15 = lane & 15;
  f32x4 acc[4][4] = {};

  for (int kk = 0; kk < FFN / 32; kk++) {
    uint4 a0 = *(const uint4*)(ap0 + kk * 32);
    uint4 a1 = *(const uint4*)(ap1 + kk * 32);
    float4 bv[4];
#pragma unroll
    for (int i = 0; i < 4; i++) bv[i] = *(const float4*)(bptr[i] + kk * 32);
    *(uint4*)&As[tr2 * 40 + tc2 * 8] = a0;
    *(uint4*)&As[(tr2 + 64) * 40 + tc2 * 8] = a1;
#pragma unroll
    for (int i = 0; i < 4; i++) {
      uint2 bp; bp.x = pk_bf16(bv[i].x, bv[i].y); bp.y = pk_bf16(bv[i].z, bv[i].w);
      *(uint2*)&Bs[(tr + 32 * i) * 40 + tc * 4] = bp;
    }
    __syncthreads();
    bf16x8 af[4], bfr[4];
#pragma unroll
    for (int mt = 0; mt < 4; mt++) {
      ushortx8 raw = *(const ushortx8*)&As[(wm * 64 + mt * 16 + l15) * 40 + quad * 8];
      af[mt] = __builtin_bit_cast(bf16x8, raw);
    }
#pragma unroll
    for (int nt = 0; nt < 4; nt++) {
      ushortx8 raw = *(const ushortx8*)&Bs[(wn * 64 + nt * 16 + l15) * 40 + quad * 8];
      bfr[nt] = __builtin_bit_cast(bf16x8, raw);
    }
#pragma unroll
    for (int mt = 0; mt < 4; mt++)
#pragma unroll
      for (int nt = 0; nt < 4; nt++)
        acc[mt][nt] = __builtin_amdgcn_mfma_f32_16x16x32_bf16(af[mt], bfr[nt], acc[mt][nt], 0, 0, 0);
    __syncthreads();
  }

  int mrem = Nexp - m0;
#pragma unroll
  for (int mt = 0; mt < 4; mt++) {
    int rbase = wm * 64 + mt * 16 + quad * 4;
#pragma unroll
    for (int nt = 0; nt < 4; nt++) {
      int col = wn * 64 + nt * 16 + l15;
      float bb = b2[e * HID + n0 + col];
#pragma unroll
      for (int r = 0; r < 4; r++) {
        int rr = rbase + r;
        if (rr < mrem) {
          float v = (acc[mt][nt][r] + bb) * wsh[rr];
          out[(size_t)toks[rr] * HID + n0 + col] = v;
        }
      }
    }
  }
}

extern "C" void kernel_launch(void* const* d_in, const int* in_sizes, int n_in,
                              void* d_out, int out_size, void* d_ws, size_t ws_size,
                              hipStream_t stream) {
  const float* x  = (const float*)d_in[0];
  const float* rw = (const float*)d_in[1];
  const float* w1 = (const float*)d_in[2];
  const float* b1 = (const float*)d_in[3];
  const float* w2 = (const float*)d_in[4];
  const float* b2 = (const float*)d_in[5];
  float* out = (float*)d_out;

  char* ws = (char*)d_ws;
  int*   counts   = (int*)(ws + 0);
  int*   cursor   = (int*)(ws + 32);
  float* prob_sum = (float*)(ws + 64);
  int*   offsets  = (int*)(ws + 96);
  int*   perm     = (int*)(ws + 256);
  float* wgt      = (float*)(ws + 256 + 16384);
  int*   eidx     = (int*)(ws + 256 + 32768);
  unsigned short* hbuf = (unsigned short*)(ws + 65536);

  hipMemsetAsync(d_ws, 0, 128, stream);
  router_kernel<<<NT / 4, 256, 0, stream>>>(x, rw, counts, prob_sum, eidx, wgt);
  scan_aux_kernel<<<1, 64, 0, stream>>>(counts, prob_sum, offsets, out + (size_t)NT * HID);
  bucketize_kernel<<<NT / 256, 256, 0, stream>>>(eidx, offsets, cursor, perm);
  gemm1_kernel<<<dim3(FFN / 128, NT / 128, NE), 256, 0, stream>>>(x, w1, b1, counts, offsets, perm, hbuf);
  gemm2_kernel<<<dim3(HID / 128, NT / 128, NE), 256, 0, stream>>>(hbuf, w2, b2, counts, offsets, perm, wgt, out);
}

// Round 3
// 553.280 us; speedup vs baseline: 1.1297x; 1.1297x over previous
//
#include <hip/hip_runtime.h>
#include <cstdint>

#define HID 1024
#define FFN 4096
#define NE 8
#define NT 4096

typedef __bf16 bf16x8 __attribute__((ext_vector_type(8)));
typedef unsigned short ushortx8 __attribute__((ext_vector_type(8)));
typedef float f32x4 __attribute__((ext_vector_type(4)));

// ---- ws layout (bytes) ----
// 0    : int   counts[8]
// 32   : int   cursor[8]
// 64   : float prob_sum[8]
// 96   : int   offsets[8]
// 256  : int   perm[NT]
// +16384: float wgt[NT]
// +32768: int  eidx[NT]
// 65536: ushort hbuf[NT*FFN]   (bf16 activations, 33.5 MB)

// round-to-nearest-even fp32->bf16 pack (verified correct in R1)
__device__ __forceinline__ unsigned cvt2(float a, float b) {
  unsigned ua = __float_as_uint(a), ub = __float_as_uint(b);
  ua = (ua + 0x7fffu + ((ua >> 16) & 1u)) >> 16;
  ub = (ub + 0x7fffu + ((ub >> 16) & 1u)) >> 16;
  return ua | (ub << 16);
}
__device__ __forceinline__ unsigned short f2bf(float a) {
  unsigned ua = __float_as_uint(a);
  return (unsigned short)((ua + 0x7fffu + ((ua >> 16) & 1u)) >> 16);
}

// ---------------- router: fp32 exact, one wave per token ----------------
__global__ __launch_bounds__(256) void router_kernel(
    const float* __restrict__ x, const float* __restrict__ rw,
    int* __restrict__ counts, float* __restrict__ prob_sum,
    int* __restrict__ eidx, float* __restrict__ wgt) {
  __shared__ float rsm[NE * HID];
  __shared__ float pshare[4][NE];
  for (int i = threadIdx.x; i < NE * HID; i += 256) rsm[i] = rw[i];
  __syncthreads();
  int wave = threadIdx.x >> 6, lane = threadIdx.x & 63;
  int t = blockIdx.x * 4 + wave;
  const float* xr = x + (size_t)t * HID;
  float acc[NE];
#pragma unroll
  for (int e = 0; e < NE; e++) acc[e] = 0.f;
#pragma unroll
  for (int j = 0; j < HID / 64; j++) {
    float xv = xr[j * 64 + lane];
#pragma unroll
    for (int e = 0; e < NE; e++) acc[e] = fmaf(xv, rsm[e * HID + j * 64 + lane], acc[e]);
  }
#pragma unroll
  for (int off = 32; off > 0; off >>= 1) {
#pragma unroll
    for (int e = 0; e < NE; e++) acc[e] += __shfl_down(acc[e], off);
  }
  if (lane == 0) {
    float mx = acc[0]; int mi = 0;
#pragma unroll
    for (int e = 1; e < NE; e++) if (acc[e] > mx) { mx = acc[e]; mi = e; }
    float pr[NE], se = 0.f;
#pragma unroll
    for (int e = 0; e < NE; e++) { pr[e] = expf(acc[e] - mx); se += pr[e]; }
    float inv = 1.f / se;
    wgt[t] = pr[mi] * inv;
    eidx[t] = mi;
    atomicAdd(&counts[mi], 1);
#pragma unroll
    for (int e = 0; e < NE; e++) pshare[wave][e] = pr[e] * inv;
  }
  __syncthreads();
  if (threadIdx.x < NE) {
    float s = pshare[0][threadIdx.x] + pshare[1][threadIdx.x] +
              pshare[2][threadIdx.x] + pshare[3][threadIdx.x];
    atomicAdd(&prob_sum[threadIdx.x], s);
  }
}

// ---------------- offsets scan + aux loss ----------------
__global__ void scan_aux_kernel(const int* __restrict__ counts,
                                const float* __restrict__ prob_sum,
                                int* __restrict__ offsets,
                                float* __restrict__ aux_out) {
  if (threadIdx.x == 0) {
    int off = 0; float s = 0.f;
    for (int e = 0; e < NE; e++) {
      offsets[e] = off;
      off += counts[e];
      s += (prob_sum[e] / (float)NT) * ((float)counts[e] / (float)NT);
    }
    *aux_out = 0.01f * (float)NE * s;
  }
}

// ---------------- group tokens by expert ----------------
__global__ void bucketize_kernel(const int* __restrict__ eidx,
                                 const int* __restrict__ offsets,
                                 int* __restrict__ cursor, int* __restrict__ perm) {
  int t = blockIdx.x * 256 + threadIdx.x;
  int e = eidx[t];
  int slot = atomicAdd(&cursor[e], 1);
  perm[offsets[e] + slot] = t;
}

// ---------------- GEMM1: H = gelu(X W1^T + b1) ----------------
// Tile M128 x N64, BK=32, LDS double-buffer + register prefetch, 1 barrier/iter.
// 4 waves 2x2: wave tile 64x32 -> 4x2 frags of 16x16x32.
__global__ __launch_bounds__(256, 4) void gemm1_kernel(
    const float* __restrict__ x, const float* __restrict__ w1,
    const float* __restrict__ b1, const int* __restrict__ counts,
    const int* __restrict__ offsets, const int* __restrict__ perm,
    unsigned short* __restrict__ hbuf) {
  int e = blockIdx.z;
  int Nexp = counts[e];
  int m0 = blockIdx.y * 128;
  if (m0 >= Nexp) return;
  int n0 = blockIdx.x * 64;
  int obase = offsets[e];
  int gbase = obase + m0;

  __shared__ unsigned short As[2][128 * 40];  // stride 40 ushort = 80B (16B aligned)
  __shared__ unsigned short Bs[2][64 * 40];
  __shared__ int toks[128];

  int tid = threadIdx.x;
  if (tid < 128) {
    int r = m0 + tid;
    toks[tid] = perm[obase + (r < Nexp ? r : Nexp - 1)];
  }
  __syncthreads();

  int tr = tid >> 3, tc = tid & 7;
  const float* w1e = w1 + (size_t)e * (FFN * HID);
  const float* aptr[4];
  const float* bptr[2];
#pragma unroll
  for (int i = 0; i < 4; i++) aptr[i] = x + (size_t)toks[tr + 32 * i] * HID + tc * 4;
#pragma unroll
  for (int i = 0; i < 2; i++) bptr[i] = w1e + (size_t)(n0 + tr + 32 * i) * HID + tc * 4;

  int lane = tid & 63, w = tid >> 6, wm = w & 1, wn = w >> 1;
  int quad = lane >> 4, l15 = lane & 15;
  f32x4 acc[4][2] = {};
  const int sidx = tr * 40 + tc * 4;

  // prologue: tile 0 -> buf 0
  {
    float4 pa[4], pb[2];
#pragma unroll
    for (int i = 0; i < 4; i++) pa[i] = *(const float4*)(aptr[i]);
#pragma unroll
    for (int i = 0; i < 2; i++) pb[i] = *(const float4*)(bptr[i]);
#pragma unroll
    for (int i = 0; i < 4; i++) {
      uint2 p; p.x = cvt2(pa[i].x, pa[i].y); p.y = cvt2(pa[i].z, pa[i].w);
      *(uint2*)&As[0][sidx + i * 32 * 40] = p;
    }
#pragma unroll
    for (int i = 0; i < 2; i++) {
      uint2 p; p.x = cvt2(pb[i].x, pb[i].y); p.y = cvt2(pb[i].z, pb[i].w);
      *(uint2*)&Bs[0][sidx + i * 32 * 40] = p;
    }
  }
  __syncthreads();

  const int NK = HID / 32;  // 32
  for (int kk = 0; kk < NK; kk++) {
    float4 na[4], nb[2];
    bool more = (kk + 1 < NK);
    if (more) {
#pragma unroll
      for (int i = 0; i < 4; i++) na[i] = *(const float4*)(aptr[i] + (kk + 1) * 32);
#pragma unroll
      for (int i = 0; i < 2; i++) nb[i] = *(const float4*)(bptr[i] + (kk + 1) * 32);
    }
    const unsigned short* Ab = As[kk & 1];
    const unsigned short* Bb = Bs[kk & 1];
    bf16x8 af[4], bfr[2];
#pragma unroll
    for (int mt = 0; mt < 4; mt++)
      af[mt] = __builtin_bit_cast(bf16x8, *(const ushortx8*)&Ab[(wm * 64 + mt * 16 + l15) * 40 + quad * 8]);
#pragma unroll
    for (int nt = 0; nt < 2; nt++)
      bfr[nt] = __builtin_bit_cast(bf16x8, *(const ushortx8*)&Bb[(wn * 32 + nt * 16 + l15) * 40 + quad * 8]);
#pragma unroll
    for (int mt = 0; mt < 4; mt++)
#pragma unroll
      for (int nt = 0; nt < 2; nt++)
        acc[mt][nt] = __builtin_amdgcn_mfma_f32_16x16x32_bf16(af[mt], bfr[nt], acc[mt][nt], 0, 0, 0);
    if (more) {
      int nbf = (kk + 1) & 1;
#pragma unroll
      for (int i = 0; i < 4; i++) {
        uint2 p; p.x = cvt2(na[i].x, na[i].y); p.y = cvt2(na[i].z, na[i].w);
        *(uint2*)&As[nbf][sidx + i * 32 * 40] = p;
      }
#pragma unroll
      for (int i = 0; i < 2; i++) {
        uint2 p; p.x = cvt2(nb[i].x, nb[i].y); p.y = cvt2(nb[i].z, nb[i].w);
        *(uint2*)&Bs[nbf][sidx + i * 32 * 40] = p;
      }
    }
    __syncthreads();
  }

  int mrem = Nexp - m0;
#pragma unroll
  for (int mt = 0; mt < 4; mt++) {
    int rbase = wm * 64 + mt * 16 + quad * 4;
#pragma unroll
    for (int nt = 0; nt < 2; nt++) {
      int col = wn * 32 + nt * 16 + l15;
      float bb = b1[e * FFN + n0 + col];
#pragma unroll
      for (int r = 0; r < 4; r++) {
        int rr = rbase + r;
        if (rr < mrem) {
          float v = acc[mt][nt][r] + bb;
          v = 0.5f * v * (1.0f + erff(v * 0.70710678118654752f));  // exact gelu
          hbuf[(size_t)(gbase + rr) * FFN + n0 + col] = f2bf(v);
        }
      }
    }
  }
}

// ---------------- GEMM2: Out += (H W2^T [+ b2]) * gate, split-K=2 ----------------
// Tile M128 x N128, BK=32, dbuf + prefetch. d_out is pre-zeroed; fp32 atomicAdd.
__global__ __launch_bounds__(256, 3) void gemm2_kernel(
    const unsigned short* __restrict__ hbuf, const float* __restrict__ w2,
    const float* __restrict__ b2, const int* __restrict__ counts,
    const int* __restrict__ offsets, const int* __restrict__ perm,
    const float* __restrict__ wgt, float* __restrict__ out) {
  int e = blockIdx.z & 7, kz = blockIdx.z >> 3;
  int Nexp = counts[e];
  int m0 = blockIdx.y * 128;
  if (m0 >= Nexp) return;
  int n0 = blockIdx.x * 128;
  int k0 = kz * (FFN / 2);
  int obase = offsets[e];
  int gbase = obase + m0;

  __shared__ unsigned short As[2][128 * 40];
  __shared__ unsigned short Bs[2][128 * 40];
  __shared__ int toks[128];
  __shared__ float wsh[128];

  int tid = threadIdx.x;
  if (tid < 128) {
    int r = m0 + tid;
    int tk = perm[obase + (r < Nexp ? r : Nexp - 1)];
    toks[tid] = tk;
    wsh[tid] = wgt[tk];
  }
  __syncthreads();

  // A staging: bf16 rows of hbuf, one uint4 (8 bf16) x2 rows per thread
  int tr2 = tid >> 2, tc2 = tid & 3;
  int g0 = gbase + tr2;      if (g0 > NT - 1) g0 = NT - 1;
  int g1 = gbase + tr2 + 64; if (g1 > NT - 1) g1 = NT - 1;
  const unsigned short* ap0 = hbuf + (size_t)g0 * FFN + k0 + tc2 * 8;
  const unsigned short* ap1 = hbuf + (size_t)g1 * FFN + k0 + tc2 * 8;

  // B staging: fp32 fc2_w rows, convert
  int tr = tid >> 3, tc = tid & 7;
  const float* w2e = w2 + (size_t)e * (HID * FFN);
  const float* bptr[4];
#pragma unroll
  for (int i = 0; i < 4; i++)
    bptr[i] = w2e + (size_t)(n0 + tr + 32 * i) * FFN + k0 + tc * 4;

  int lane = tid & 63, w = tid >> 6, wm = w & 1, wn = w >> 1;
  int quad = lane >> 4, l15 = lane & 15;
  f32x4 acc[4][4] = {};
  const int sa = tr2 * 40 + tc2 * 8;
  const int sb = tr * 40 + tc * 4;

  // prologue
  {
    uint4 a0 = *(const uint4*)ap0;
    uint4 a1 = *(const uint4*)ap1;
    *(uint4*)&As[0][sa] = a0;
    *(uint4*)&As[0][sa + 64 * 40] = a1;
#pragma unroll
    for (int i = 0; i < 4; i++) {
      float4 bv = *(const float4*)bptr[i];
      uint2 p; p.x = cvt2(bv.x, bv.y); p.y = cvt2(bv.z, bv.w);
      *(uint2*)&Bs[0][sb + i * 32 * 40] = p;
    }
  }
  __syncthreads();

  const int NK = (FFN / 2) / 32;  // 64
  for (int kk = 0; kk < NK; kk++) {
    uint4 na0, na1; float4 nb[4];
    bool more = (kk + 1 < NK);
    if (more) {
      na0 = *(const uint4*)(ap0 + (kk + 1) * 32);
      na1 = *(const uint4*)(ap1 + (kk + 1) * 32);
#pragma unroll
      for (int i = 0; i < 4; i++) nb[i] = *(const float4*)(bptr[i] + (kk + 1) * 32);
    }
    const unsigned short* Ab = As[kk & 1];
    const unsigned short* Bb = Bs[kk & 1];
    bf16x8 af[4], bfr[4];
#pragma unroll
    for (int mt = 0; mt < 4; mt++)
      af[mt] = __builtin_bit_cast(bf16x8, *(const ushortx8*)&Ab[(wm * 64 + mt * 16 + l15) * 40 + quad * 8]);
#pragma unroll
    for (int nt = 0; nt < 4; nt++)
      bfr[nt] = __builtin_bit_cast(bf16x8, *(const ushortx8*)&Bb[(wn * 64 + nt * 16 + l15) * 40 + quad * 8]);
#pragma unroll
    for (int mt = 0; mt < 4; mt++)
#pragma unroll
      for (int nt = 0; nt < 4; nt++)
        acc[mt][nt] = __builtin_amdgcn_mfma_f32_16x16x32_bf16(af[mt], bfr[nt], acc[mt][nt], 0, 0, 0);
    if (more) {
      int nbf = (kk + 1) & 1;
      *(uint4*)&As[nbf][sa] = na0;
      *(uint4*)&As[nbf][sa + 64 * 40] = na1;
#pragma unroll
      for (int i = 0; i < 4; i++) {
        uint2 p; p.x = cvt2(nb[i].x, nb[i].y); p.y = cvt2(nb[i].z, nb[i].w);
        *(uint2*)&Bs[nbf][sb + i * 32 * 40] = p;
      }
    }
    __syncthreads();
  }

  int mrem = Nexp - m0;
#pragma unroll
  for (int mt = 0; mt < 4; mt++) {
    int rbase = wm * 64 + mt * 16 + quad * 4;
#pragma unroll
    for (int nt = 0; nt < 4; nt++) {
      int col = wn * 64 + nt * 16 + l15;
      float bb = b2[e * HID + n0 + col];
#pragma unroll
      for (int r = 0; r < 4; r++) {
        int rr = rbase + r;
        if (rr < mrem) {
          float v = acc[mt][nt][r];
          if (kz == 0) v += bb;
          atomicAdd(out + (size_t)toks[rr] * HID + n0 + col, v * wsh[rr]);
        }
      }
    }
  }
}

extern "C" void kernel_launch(void* const* d_in, const int* in_sizes, int n_in,
                              void* d_out, int out_size, void* d_ws, size_t ws_size,
                              hipStream_t stream) {
  const float* x  = (const float*)d_in[0];
  const float* rw = (const float*)d_in[1];
  const float* w1 = (const float*)d_in[2];
  const float* b1 = (const float*)d_in[3];
  const float* w2 = (const float*)d_in[4];
  const float* b2 = (const float*)d_in[5];
  float* out = (float*)d_out;

  char* ws = (char*)d_ws;
  int*   counts   = (int*)(ws + 0);
  int*   cursor   = (int*)(ws + 32);
  float* prob_sum = (float*)(ws + 64);
  int*   offsets  = (int*)(ws + 96);
  int*   perm     = (int*)(ws + 256);
  float* wgt      = (float*)(ws + 256 + 16384);
  int*   eidx     = (int*)(ws + 256 + 32768);
  unsigned short* hbuf = (unsigned short*)(ws + 65536);

  (void)hipMemsetAsync(d_ws, 0, 128, stream);
  (void)hipMemsetAsync(d_out, 0, (size_t)(NT * HID + 1) * sizeof(float), stream);
  router_kernel<<<NT / 4, 256, 0, stream>>>(x, rw, counts, prob_sum, eidx, wgt);
  scan_aux_kernel<<<1, 64, 0, stream>>>(counts, prob_sum, offsets, out + (size_t)NT * HID);
  bucketize_kernel<<<NT / 256, 256, 0, stream>>>(eidx, offsets, cursor, perm);
  gemm1_kernel<<<dim3(FFN / 64, NT / 128, NE), 256, 0, stream>>>(x, w1, b1, counts, offsets, perm, hbuf);
  gemm2_kernel<<<dim3(HID / 128, NT / 128, NE * 2), 256, 0, stream>>>(hbuf, w2, b2, counts, offsets, perm, wgt, out);
}